// Round 19
// baseline (314.149 us; speedup 1.0000x reference)
//
#include <hip/hip_runtime.h>
#include <hip/hip_bf16.h>
#include <math.h>

typedef unsigned short u16;
typedef __bf16 bf16x8 __attribute__((ext_vector_type(8)));
typedef float f32x4 __attribute__((ext_vector_type(4)));
typedef float f32x16 __attribute__((ext_vector_type(16)));

#define NB 32
#define LSEQ 1024
#define DIN 512
#define EDIM 1024
#define SDIM 128
#define NTOK (NB * LSEQ)       // 32768
#define NUV 2176               // 2E + S
#define CHUNK 16               // batches per qk/pv chunk

#define AS1 __attribute__((address_space(1)))
#define AS3 __attribute__((address_space(3)))

__device__ __forceinline__ u16 f2bf(float f) {
  unsigned u = __builtin_bit_cast(unsigned, f);
  u += 0x7fffu + ((u >> 16) & 1u);
  return (u16)(u >> 16);
}
__device__ __forceinline__ float bf2f(u16 h) {
  unsigned u = ((unsigned)h) << 16;
  return __builtin_bit_cast(float, u);
}
__device__ __forceinline__ float fast_silu(float x) {
  float t = __builtin_amdgcn_exp2f(-1.44269504088896f * x);
  return x * __builtin_amdgcn_rcpf(1.0f + t);
}

// ---------------- small prep kernels ----------------

__global__ __launch_bounds__(256) void k_f32_to_bf16(const float* __restrict__ in,
                                                     u16* __restrict__ out, int n4) {
  int i = blockIdx.x * 256 + threadIdx.x;
  if (i < n4) {
    float4 f = ((const float4*)in)[i];
    ushort4 o;
    o.x = f2bf(f.x); o.y = f2bf(f.y); o.z = f2bf(f.z); o.w = f2bf(f.w);
    ((ushort4*)out)[i] = o;
  }
}

// fused rms-norm + half-shift (reads x once; verified R5)
__global__ __launch_bounds__(256) void k_normshift(const float* __restrict__ x,
                                                   const float* __restrict__ g,
                                                   u16* __restrict__ xn2) {
  int t = blockIdx.x;
  int l = t & (LSEQ - 1);
  float2 v = ((const float2*)(x + (size_t)t * DIN))[threadIdx.x];
  float ss = v.x * v.x + v.y * v.y;
  for (int o = 32; o > 0; o >>= 1) ss += __shfl_down(ss, o, 64);
  __shared__ float p[4];
  if ((threadIdx.x & 63) == 0) p[threadIdx.x >> 6] = ss;
  __syncthreads();
  float s = p[0] + p[1] + p[2] + p[3];
  float norm = sqrtf(s * (1.0f / (float)DIN));
  float inv = g[0] / fmaxf(norm, 1e-5f);
  int d = threadIdx.x * 2;
  ushort2 ob; ob.x = f2bf(v.x * inv); ob.y = f2bf(v.y * inv);
  if (d >= 256) {
    *(ushort2*)(xn2 + (size_t)t * DIN + d) = ob;
  } else {
    if (l < LSEQ - 1) *(ushort2*)(xn2 + (size_t)(t + 1) * DIN + d) = ob;
    if (l == 0) { ushort2 z = {0, 0}; *(ushort2*)(xn2 + (size_t)t * DIN + d) = z; }
  }
}

// RoPE tables in double precision (match numpy)
__global__ __launch_bounds__(256) void k_rope_table(float* __restrict__ sin_t,
                                                    float* __restrict__ cos_t) {
  int idx = blockIdx.x * 256 + threadIdx.x;   // 1024*64
  int l = idx >> 6, j = idx & 63;
  double freq = pow(10000.0, (double)j / 64.0);
  float arg = (float)l * (float)freq;
  double a = (double)arg;
  sin_t[idx] = (float)sin(a);
  cos_t[idx] = (float)cos(a);
}

// ======== shared staging macros (identical in both cores; R11-verified) ========

#define GROW_A(s) (wr * 128 + (s) * 32 + wc * 8)
#define GROW_B(s) (wid * 32 + (s) * 8)

#define STG_PAIR(s, At2, Bt2, dA, dB)                                              \
  do {                                                                             \
    __builtin_amdgcn_global_load_lds(                                              \
        (AS1 unsigned int*)((At2) + (size_t)(GROW_A(s) + srow) * lda + scol),      \
        (AS3 unsigned int*)((dA) + GROW_A(s) * 64), 16, 0, 0);                     \
    __builtin_amdgcn_global_load_lds(                                              \
        (AS1 unsigned int*)((Bt2) + (size_t)(GROW_B(s) + srow) * ldb + scol),      \
        (AS3 unsigned int*)((dB) + GROW_B(s) * 64), 16, 0, 0);                     \
  } while (0)

#define BAR_FENCE()                                                                \
  do { __builtin_amdgcn_s_barrier(); asm volatile("" ::: "memory"); } while (0)

// ======== core A: 16x16x32 MFMA double-buffer (R13-verified; 0 conflicts) — uv ========

#define RD_A16(dst, cbuf, q)                                                       \
  do {                                                                             \
    _Pragma("unroll") for (int r_ = 0; r_ < 2; ++r_)                               \
    _Pragma("unroll") for (int h_ = 0; h_ < 2; ++h_)                               \
      dst[r_][h_] = *(const bf16x8*)((cbuf) + (wr * 128 + (q) * 32 + r_ * 16 + fr) * 64 + \
                                     (((h_ * 4 + kg) ^ fr7) * 8));                 \
  } while (0)

#define RD_B16(cbuf)                                                               \
  do {                                                                             \
    _Pragma("unroll") for (int n_ = 0; n_ < 4; ++n_)                               \
    _Pragma("unroll") for (int h_ = 0; h_ < 2; ++h_)                               \
      breg[n_][h_] = *(const bf16x8*)((cbuf) + (wc * 64 + n_ * 16 + fr) * 64 +     \
                                      (((h_ * 4 + kg) ^ fr7) * 8));                \
  } while (0)

#define MFMA16T(s, areg)                                                           \
  do {                                                                             \
    __builtin_amdgcn_s_setprio(1);                                                 \
    _Pragma("unroll") for (int r_ = 0; r_ < 2; ++r_)                               \
    _Pragma("unroll") for (int n_ = 0; n_ < 4; ++n_)                               \
    _Pragma("unroll") for (int h_ = 0; h_ < 2; ++h_)                               \
      acc[(s) * 2 + r_][n_] = __builtin_amdgcn_mfma_f32_16x16x32_bf16(             \
          areg[r_][h_], breg[n_][h_], acc[(s) * 2 + r_][n_], 0, 0, 0);             \
    __builtin_amdgcn_s_setprio(0);                                                 \
  } while (0)

#define TILE_STEP16(CA, CB, OA, OB, T)                                             \
  do {                                                                             \
    const bool st_ = ((T) + 2) < nt;                                               \
    const bool more_ = ((T) + 1) < nt;                                             \
    const u16* At2_ = A + (size_t)((T) + 2) * 64;                                  \
    const u16* Bt2_ = B + (size_t)((T) + 2) * 64;                                  \
    MFMA16T(0, ac);                                                                \
    RD_A16(an, CA, 1);                                                             \
    BAR_FENCE();                                                                   \
    if (st_) STG_PAIR(0, At2_, Bt2_, CA, CB);                                      \
    MFMA16T(1, an);                                                                \
    RD_A16(ac, CA, 2);                                                             \
    BAR_FENCE();                                                                   \
    if (st_) STG_PAIR(1, At2_, Bt2_, CA, CB);                                      \
    MFMA16T(2, ac);                                                                \
    RD_A16(an, CA, 3);                                                             \
    BAR_FENCE();                                                                   \
    if (st_) STG_PAIR(2, At2_, Bt2_, CA, CB);                                      \
    MFMA16T(3, an);                                                                \
    if (st_) asm volatile("s_waitcnt vmcnt(6)" ::: "memory");                      \
    else     asm volatile("s_waitcnt vmcnt(0)" ::: "memory");                      \
    BAR_FENCE();                                                                   \
    if (st_) STG_PAIR(3, At2_, Bt2_, CA, CB);                                      \
    if (more_) { RD_B16(OB); RD_A16(ac, OA, 0); }                                  \
  } while (0)

__device__ __forceinline__ void gemm256p16(const u16* __restrict__ A, int lda,
                                           const u16* __restrict__ B, int ldb,
                                           int K, u16* smem, f32x4 (&acc)[8][4]) {
  const int tid = threadIdx.x;
  const int lane = tid & 63, wid = tid >> 6;
  const int wr = wid >> 2, wc = wid & 3;
  const int fr = lane & 15, kg = lane >> 4, fr7 = fr & 7;
  const int srow = lane >> 3;
  const int scol = ((lane & 7) ^ srow) * 8;
  u16* const A0 = smem;
  u16* const B0 = smem + 16384;
  u16* const A1 = smem + 32768;
  u16* const B1 = smem + 49152;
  const int nt = K >> 6;

#pragma unroll
  for (int s = 0; s < 4; ++s) STG_PAIR(s, A, B, A0, B0);
#pragma unroll
  for (int s = 0; s < 4; ++s) STG_PAIR(s, A + 64, B + 64, A1, B1);
  asm volatile("s_waitcnt vmcnt(8)" ::: "memory");
  BAR_FENCE();

  bf16x8 breg[4][2], ac[2][2], an[2][2];
  RD_B16(B0);
  RD_A16(ac, A0, 0);

  for (int tt = 0; tt < nt; tt += 2) {
    TILE_STEP16(A0, B0, A1, B1, tt);
    TILE_STEP16(A1, B1, A0, B0, tt + 1);
  }
}

// ======== core B: 32x32x16 MFMA double-buffer (R14/R15-verified) — qk/pv/out ========

#define RD_A32(dst, cbuf, q)                                                       \
  do {                                                                             \
    _Pragma("unroll") for (int kk_ = 0; kk_ < 4; ++kk_)                            \
      dst[kk_] = *(const bf16x8*)((cbuf) + (wr * 128 + (q) * 32 + l31) * 64 +      \
                                  (((kk_ * 2 + hi) ^ l7) * 8));                    \
  } while (0)

#define RD_B32(cbuf)                                                               \
  do {                                                                             \
    _Pragma("unroll") for (int np_ = 0; np_ < 2; ++np_)                            \
    _Pragma("unroll") for (int kk_ = 0; kk_ < 4; ++kk_)                            \
      breg[np_][kk_] = *(const bf16x8*)((cbuf) + (wc * 64 + np_ * 32 + l31) * 64 + \
                                        (((kk_ * 2 + hi) ^ l7) * 8));              \
  } while (0)

#define MFMA8(s, areg)                                                             \
  do {                                                                             \
    __builtin_amdgcn_s_setprio(1);                                                 \
    _Pragma("unroll") for (int kk_ = 0; kk_ < 4; ++kk_)                            \
    _Pragma("unroll") for (int np_ = 0; np_ < 2; ++np_)                            \
      acc[s][np_] = __builtin_amdgcn_mfma_f32_32x32x16_bf16(                       \
          areg[kk_], breg[np_][kk_], acc[s][np_], 0, 0, 0);                        \
    __builtin_amdgcn_s_setprio(0);                                                 \
  } while (0)

#define TILE_STEP32(CA, CB, OA, OB, T)                                             \
  do {                                                                             \
    const bool st_ = ((T) + 2) < nt;                                               \
    const bool more_ = ((T) + 1) < nt;                                             \
    const u16* At2_ = A + (size_t)((T) + 2) * 64;                                  \
    const u16* Bt2_ = B + (size_t)((T) + 2) * 64;                                  \
    MFMA8(0, ac);                                                                  \
    RD_A32(an, CA, 1);                                                             \
    BAR_FENCE();                                                                   \
    if (st_) STG_PAIR(0, At2_, Bt2_, CA, CB);                                      \
    MFMA8(1, an);                                                                  \
    RD_A32(ac, CA, 2);                                                             \
    BAR_FENCE();                                                                   \
    if (st_) STG_PAIR(1, At2_, Bt2_, CA, CB);                                      \
    MFMA8(2, ac);                                                                  \
    RD_A32(an, CA, 3);                                                             \
    BAR_FENCE();                                                                   \
    if (st_) STG_PAIR(2, At2_, Bt2_, CA, CB);                                      \
    MFMA8(3, an);                                                                  \
    if (st_) asm volatile("s_waitcnt vmcnt(6)" ::: "memory");                      \
    else     asm volatile("s_waitcnt vmcnt(0)" ::: "memory");                      \
    BAR_FENCE();                                                                   \
    if (st_) STG_PAIR(3, At2_, Bt2_, CA, CB);                                      \
    if (more_) { RD_B32(OB); RD_A32(ac, OA, 0); }                                  \
  } while (0)

__device__ __forceinline__ void gemm256p32(const u16* __restrict__ A, int lda,
                                           const u16* __restrict__ B, int ldb,
                                           int K, u16* smem, f32x16 (&acc)[4][2]) {
  const int tid = threadIdx.x;
  const int lane = tid & 63, wid = tid >> 6;
  const int wr = wid >> 2, wc = wid & 3;
  const int l31 = lane & 31, hi = lane >> 5, l7 = lane & 7;
  const int srow = lane >> 3;
  const int scol = ((lane & 7) ^ srow) * 8;
  u16* const A0 = smem;
  u16* const B0 = smem + 16384;
  u16* const A1 = smem + 32768;
  u16* const B1 = smem + 49152;
  const int nt = K >> 6;

#pragma unroll
  for (int s = 0; s < 4; ++s) STG_PAIR(s, A, B, A0, B0);
#pragma unroll
  for (int s = 0; s < 4; ++s) STG_PAIR(s, A + 64, B + 64, A1, B1);
  asm volatile("s_waitcnt vmcnt(8)" ::: "memory");
  BAR_FENCE();

  bf16x8 breg[2][4], ac[4], an[4];
  RD_B32(B0);
  RD_A32(ac, A0, 0);

  for (int tt = 0; tt < nt; tt += 2) {
    TILE_STEP32(A0, B0, A1, B1, tt);
    TILE_STEP32(A1, B1, A0, B0, tt + 1);
  }
}

// GEMM1: uv = silu(xn2 @ uv_w^T). 16x16 core. Grid 1152 = 8 XCDs x 16 M x 9 N.
// N-tiles 0-3 -> u; 4-7 -> vt[b][e][l]; tile 8 -> fused gamma/beta+RoPE -> q,k.
__global__ __launch_bounds__(512, 2) void k_gemm_uv(const u16* __restrict__ xn2,
                                                    const u16* __restrict__ wbf,
                                                    u16* __restrict__ u, u16* __restrict__ vt,
                                                    const float* __restrict__ gamma,
                                                    const float* __restrict__ beta,
                                                    const float* __restrict__ sin_t,
                                                    const float* __restrict__ cos_t,
                                                    u16* __restrict__ qout,
                                                    u16* __restrict__ kout) {
  __shared__ __align__(16) u16 smem[65536];
  f32x4 acc[8][4] = {};
  int bid = blockIdx.x;
  int xcd = bid & 7;
  int off = bid >> 3;                 // 0..143
  int m0 = (xcd * 16 + off / 9) * 256;
  int n0 = (off % 9) * 256;
  gemm256p16(xn2 + (size_t)m0 * DIN, DIN, wbf + (size_t)n0 * DIN, DIN, DIN, smem, acc);
  int lane = threadIdx.x & 63, wid = threadIdx.x >> 6;
  int wr = wid >> 2, wc = wid & 3;
  int cb = n0 + wc * 64 + (lane & 15);
  int rb = m0 + wr * 128 + (lane >> 4) * 4;
  if (n0 < EDIM) {                       // u columns
#pragma unroll
    for (int mm = 0; mm < 8; ++mm)
#pragma unroll
      for (int n = 0; n < 4; ++n) {
        int c = cb + n * 16;
#pragma unroll
        for (int j = 0; j < 4; ++j) {
          int r = rb + mm * 16 + j;
          u[(size_t)r * EDIM + c] = f2bf(fast_silu(acc[mm][n][j]));
        }
      }
  } else if (n0 < 2 * EDIM) {            // v columns -> transposed store
    int b = m0 >> 10;
    u16* vtb = vt + (size_t)b * (EDIM * LSEQ);
#pragma unroll
    for (int mm = 0; mm < 8; ++mm) {
      int l0 = (rb + mm * 16) & (LSEQ - 1);
#pragma unroll
      for (int n = 0; n < 4; ++n) {
        int e = cb + n * 16 - EDIM;
        ushort4 o;
        o.x = f2bf(fast_silu(acc[mm][n][0]));
        o.y = f2bf(fast_silu(acc[mm][n][1]));
        o.z = f2bf(fast_silu(acc[mm][n][2]));
        o.w = f2bf(fast_silu(acc[mm][n][3]));
        *(ushort4*)(vtb + (size_t)e * LSEQ + l0) = o;
      }
    }
  } else {                               // base tile -> fused gamma/beta + RoPE -> q,k
    u16* sbase = smem;                   // [256][136] padded
    if (wc < 2) {
#pragma unroll
      for (int mm = 0; mm < 8; ++mm)
#pragma unroll
        for (int n = 0; n < 4; ++n) {
          int c = wc * 64 + (lane & 15) + n * 16;      // 0..127 local
#pragma unroll
          for (int j = 0; j < 4; ++j) {
            int r = wr * 128 + mm * 16 + (lane >> 4) * 4 + j;  // 0..255 local
            sbase[r * 136 + c] = f2bf(fast_silu(acc[mm][n][j]));
          }
        }
    }
    __syncthreads();
    int tid = threadIdx.x;
    int j = tid & 63;
    float g0 = gamma[j], g1 = gamma[64 + j], g2 = gamma[128 + j], g3 = gamma[192 + j];
    float e0 = beta[j],  e1 = beta[64 + j],  e2 = beta[128 + j],  e3 = beta[192 + j];
#pragma unroll 4
    for (int i = 0; i < 32; ++i) {
      int row = (tid >> 6) + i * 8;      // covers 0..255
      int t = m0 + row;
      int l = t & (LSEQ - 1);
      float b1 = bf2f(sbase[row * 136 + j]);
      float b2 = bf2f(sbase[row * 136 + j + 64]);
      float sn = sin_t[l * 64 + j], cs = cos_t[l * 64 + j];
      float y1 = b1 * g0 + e0, y2 = b2 * g1 + e1;
      qout[(size_t)t * SDIM + j]      = f2bf(y1 * cs - y2 * sn);
      qout[(size_t)t * SDIM + j + 64] = f2bf(y2 * cs + y1 * sn);
      y1 = b1 * g2 + e2; y2 = b2 * g3 + e3;
      kout[(size_t)t * SDIM + j]      = f2bf(y1 * cs - y2 * sn);
      kout[(size_t)t * SDIM + j + 64] = f2bf(y2 * cs + y1 * sn);
    }
  }
}

// 32x32 C/D layout: r = m0 + wr*128 + q*32 + g*8 + hi*4 + j (reg g*4+j);
//                   c = n0 + wc*64 + np*32 + l31

// GEMM2: scores = relu((q k^T + w)/sqrt(S))^2.  32x32 core, nt=2.
// Grid 256 = 8 XCDs x 2 batches x 16 tiles (16 batches per launch).
__global__ __launch_bounds__(512, 2) void k_gemm_qk(const u16* __restrict__ q_,
                                                    const u16* __restrict__ k_,
                                                    const float* __restrict__ w,
                                                    u16* __restrict__ scores) {
  __shared__ __align__(16) u16 smem[65536];
  f32x16 acc[4][2] = {};
  int bid = blockIdx.x;
  int xcd = bid & 7;
  int off = bid >> 3;                    // 0..31
  int b = xcd * 2 + (off >> 4);          // chunk-local batch
  int t = off & 15;
  int m0 = (t >> 2) * 256, n0 = (t & 3) * 256;
  gemm256p32(q_ + (size_t)(b * LSEQ + m0) * SDIM, SDIM,
             k_ + (size_t)(b * LSEQ + n0) * SDIM, SDIM,
             SDIM, smem, acc);
  int lane = threadIdx.x & 63, wid = threadIdx.x >> 6;
  int wr = wid >> 2, wc = wid & 3;
  int l31 = lane & 31, hi = lane >> 5;
  const float inv_sqrt_s = 0.08838834764831845f;
  u16* sc_b = scores + (size_t)b * LSEQ * LSEQ;
#pragma unroll
  for (int q = 0; q < 4; ++q)
#pragma unroll
    for (int np = 0; np < 2; ++np) {
      int c = n0 + wc * 64 + np * 32 + l31;
#pragma unroll
      for (int g = 0; g < 4; ++g)
#pragma unroll
        for (int j = 0; j < 4; ++j) {
          int r = m0 + wr * 128 + q * 32 + g * 8 + hi * 4 + j;
          float val = (acc[q][np][g * 4 + j] + w[c - r + (LSEQ - 1)]) * inv_sqrt_s;
          val = fmaxf(val, 0.0f);
          sc_b[(size_t)r * LSEQ + c] = f2bf(val * val);
        }
    }
}

// GEMM3: u_io <- u_io .* (scores @ v).  32x32 core.
// Grid 256 = 8 XCDs x 2 batches x 16 tiles (16 batches per launch).
__global__ __launch_bounds__(512, 2) void k_gemm_pv(const u16* __restrict__ scores,
                                                    const u16* __restrict__ vt,
                                                    u16* u_io) {
  __shared__ __align__(16) u16 smem[65536];
  f32x16 acc[4][2] = {};
  int bid = blockIdx.x;
  int xcd = bid & 7;
  int off = bid >> 3;                    // 0..31
  int b = xcd * 2 + (off >> 4);          // chunk-local batch
  int t = off & 15;
  int m0 = (t >> 2) * 256, n0 = (t & 3) * 256;
  gemm256p32(scores + (size_t)b * LSEQ * LSEQ + (size_t)m0 * LSEQ, LSEQ,
             vt + (size_t)b * LSEQ * EDIM + (size_t)n0 * LSEQ, LSEQ,
             LSEQ, smem, acc);
  int lane = threadIdx.x & 63, wid = threadIdx.x >> 6;
  int wr = wid >> 2, wc = wid & 3;
  int l31 = lane & 31, hi = lane >> 5;
#pragma unroll
  for (int q = 0; q < 4; ++q)
#pragma unroll
    for (int np = 0; np < 2; ++np) {
      int c = n0 + wc * 64 + np * 32 + l31;
#pragma unroll
      for (int g = 0; g < 4; ++g)
#pragma unroll
        for (int j = 0; j < 4; ++j) {
          int r = m0 + wr * 128 + q * 32 + g * 8 + hi * 4 + j;
          size_t idx = (size_t)(b * LSEQ + r) * EDIM + c;
          u_io[idx] = f2bf(acc[q][np][g * 4 + j] * bf2f(u_io[idx]));
        }
    }
}

// GEMM4: out = x*res_scale + (attn @ o_w^T)*layer_scale.  32x32 core.
// Grid 256 = 8 XCDs x 16 M-tiles x 2 N-tiles.
__global__ __launch_bounds__(512, 2) void k_gemm_out(const u16* __restrict__ attn,
                                                     const u16* __restrict__ owbf,
                                                     const float* __restrict__ x,
                                                     const float* __restrict__ res_scale,
                                                     const float* __restrict__ layer_scale,
                                                     float* __restrict__ out) {
  __shared__ __align__(16) u16 smem[65536];
  f32x16 acc[4][2] = {};
  int bid = blockIdx.x;
  int xcd = bid & 7;
  int off = bid >> 3;                 // 0..31
  int m0 = (xcd * 16 + (off >> 1)) * 256;
  int n0 = (off & 1) * 256;
  gemm256p32(attn + (size_t)m0 * EDIM, EDIM, owbf + (size_t)n0 * EDIM, EDIM,
             EDIM, smem, acc);
  int lane = threadIdx.x & 63, wid = threadIdx.x >> 6;
  int wr = wid >> 2, wc = wid & 3;
  int l31 = lane & 31, hi = lane >> 5;
#pragma unroll
  for (int q = 0; q < 4; ++q)
#pragma unroll
    for (int np = 0; np < 2; ++np) {
      int c = n0 + wc * 64 + np * 32 + l31;
#pragma unroll
      for (int g = 0; g < 4; ++g)
#pragma unroll
        for (int j = 0; j < 4; ++j) {
          int r = m0 + wr * 128 + q * 32 + g * 8 + hi * 4 + j;
          out[(size_t)r * DIN + c] =
              x[(size_t)r * DIN + c] * res_scale[c] + acc[q][np][g * 4 + j] * layer_scale[c];
        }
    }
}

// ---------------- launch ----------------

extern "C" void kernel_launch(void* const* d_in, const int* in_sizes, int n_in,
                              void* d_out, int out_size, void* d_ws, size_t ws_size,
                              hipStream_t stream) {
  const float* x          = (const float*)d_in[0];
  const float* uv_w       = (const float*)d_in[1];
  const float* o_w        = (const float*)d_in[2];
  const float* gamma      = (const float*)d_in[3];
  const float* beta       = (const float*)d_in[4];
  const float* w          = (const float*)d_in[5];
  const float* g          = (const float*)d_in[6];
  const float* res_scale  = (const float*)d_in[7];
  const float* layer_scale= (const float*)d_in[8];
  float* out = (float*)d_out;

  char* ws = (char*)d_ws;
  // workspace layout (bytes), peak ~180 MB (< proven-good 197).
  u16* xn2    = (u16*)(ws + 0);            // 32 MB, dead after gemm_uv
  u16* scores = (u16*)(ws + 0);            // 32 MB (aliases dead xn2)
  u16* q      = (u16*)(ws + 33554432);     // 8 MB
  u16* k      = (u16*)(ws + 41943040);     // 8 MB
  u16* u_io   = (u16*)(ws + 50331648);     // 64 MB: u, gated in place -> attn
  u16* vt     = (u16*)(ws + 117440512);    // 64 MB: v^T per batch
  u16* uvw_bf = (u16*)(ws + 184549376);    // 2.125 MB (+slack for tile-8 pad reads)
  u16* ow_bf  = (u16*)(ws + 187170816);    // 1 MB
  float* sin_t = (float*)(ws + 188219392); // 256 KB
  float* cos_t = (float*)(ws + 188481536); // 256 KB

  // prep
  k_f32_to_bf16<<<dim3((NUV * DIN / 4 + 255) / 256), 256, 0, stream>>>(uv_w, uvw_bf, NUV * DIN / 4);
  k_f32_to_bf16<<<dim3((DIN * EDIM / 4 + 255) / 256), 256, 0, stream>>>(o_w, ow_bf, DIN * EDIM / 4);
  k_rope_table<<<dim3(LSEQ * 64 / 256), 256, 0, stream>>>(sin_t, cos_t);
  k_normshift<<<dim3(NTOK), 256, 0, stream>>>(x, g, xn2);

  // uv projection + silu + fused qk build (16x16 core)
  k_gemm_uv<<<dim3(1152), 512, 0, stream>>>(xn2, uvw_bf, u_io, vt,
                                            gamma, beta, sin_t, cos_t, q, k);

  // scores + pv, chunked by 16 batches (32x32 core)
  for (int ch = 0; ch < NB / CHUNK; ++ch) {
    size_t tok0 = (size_t)ch * CHUNK * LSEQ;
    k_gemm_qk<<<dim3(256), 512, 0, stream>>>(q + tok0 * SDIM, k + tok0 * SDIM, w, scores);
    k_gemm_pv<<<dim3(256), 512, 0, stream>>>(scores, vt + tok0 * EDIM, u_io + tok0 * EDIM);
  }

  // final projection + residual (32x32 core)
  k_gemm_out<<<dim3(256), 512, 0, stream>>>(u_io, ow_bf, x, res_scale, layer_scale, out);
}

// Round 20
// 298.675 us; speedup vs baseline: 1.0518x; 1.0518x over previous
//
#include <hip/hip_runtime.h>
#include <hip/hip_bf16.h>
#include <math.h>

typedef unsigned short u16;
typedef __bf16 bf16x8 __attribute__((ext_vector_type(8)));
typedef float f32x4 __attribute__((ext_vector_type(4)));
typedef float f32x16 __attribute__((ext_vector_type(16)));

#define NB 32
#define LSEQ 1024
#define DIN 512
#define EDIM 1024
#define SDIM 128
#define NTOK (NB * LSEQ)       // 32768
#define NUV 2176               // 2E + S
#define CHUNK 16               // batches per qk/pv chunk

#define AS1 __attribute__((address_space(1)))
#define AS3 __attribute__((address_space(3)))

__device__ __forceinline__ u16 f2bf(float f) {
  unsigned u = __builtin_bit_cast(unsigned, f);
  u += 0x7fffu + ((u >> 16) & 1u);
  return (u16)(u >> 16);
}
__device__ __forceinline__ float bf2f(u16 h) {
  unsigned u = ((unsigned)h) << 16;
  return __builtin_bit_cast(float, u);
}
__device__ __forceinline__ float fast_silu(float x) {
  float t = __builtin_amdgcn_exp2f(-1.44269504088896f * x);
  return x * __builtin_amdgcn_rcpf(1.0f + t);
}

// ---------------- small prep kernels ----------------

// both weight conversions in one launch (uv_w then o_w)
__global__ __launch_bounds__(256) void k_wconv(const float* __restrict__ in1,
                                               u16* __restrict__ out1, int n1_4,
                                               const float* __restrict__ in2,
                                               u16* __restrict__ out2, int n2_4) {
  int i = blockIdx.x * 256 + threadIdx.x;
  if (i < n1_4) {
    float4 f = ((const float4*)in1)[i];
    ushort4 o;
    o.x = f2bf(f.x); o.y = f2bf(f.y); o.z = f2bf(f.z); o.w = f2bf(f.w);
    ((ushort4*)out1)[i] = o;
  } else if (i - n1_4 < n2_4) {
    int j = i - n1_4;
    float4 f = ((const float4*)in2)[j];
    ushort4 o;
    o.x = f2bf(f.x); o.y = f2bf(f.y); o.z = f2bf(f.z); o.w = f2bf(f.w);
    ((ushort4*)out2)[j] = o;
  }
}

// fused rms-norm + half-shift, one WAVE per token (4 tokens/block, grid 8192).
// Lane reads 32B (2x float4), shfl_xor butterfly reduce (no LDS), 16B stores.
__global__ __launch_bounds__(256) void k_normshift(const float* __restrict__ x,
                                                   const float* __restrict__ g,
                                                   u16* __restrict__ xn2) {
  int t = (blockIdx.x << 2) + (threadIdx.x >> 6);   // token
  int lane = threadIdx.x & 63;
  int l = t & (LSEQ - 1);
  const float* xr = x + (size_t)t * DIN + lane * 8;
  float4 a = *(const float4*)xr;
  float4 b = *(const float4*)(xr + 4);
  float ss = a.x * a.x + a.y * a.y + a.z * a.z + a.w * a.w
           + b.x * b.x + b.y * b.y + b.z * b.z + b.w * b.w;
#pragma unroll
  for (int o = 32; o > 0; o >>= 1) ss += __shfl_xor(ss, o, 64);
  float norm = sqrtf(ss * (1.0f / (float)DIN));
  float inv = g[0] / fmaxf(norm, 1e-5f);
  ushort4 o0, o1;
  o0.x = f2bf(a.x * inv); o0.y = f2bf(a.y * inv); o0.z = f2bf(a.z * inv); o0.w = f2bf(a.w * inv);
  o1.x = f2bf(b.x * inv); o1.y = f2bf(b.y * inv); o1.z = f2bf(b.z * inv); o1.w = f2bf(b.w * inv);
  int d = lane * 8;
  if (d >= 256) {                         // own second half
    *(ushort4*)(xn2 + (size_t)t * DIN + d) = o0;
    *(ushort4*)(xn2 + (size_t)t * DIN + d + 4) = o1;
  } else {
    if (l < LSEQ - 1) {                   // shifted into next token's first half
      *(ushort4*)(xn2 + (size_t)(t + 1) * DIN + d) = o0;
      *(ushort4*)(xn2 + (size_t)(t + 1) * DIN + d + 4) = o1;
    }
    if (l == 0) {                         // zero own first half
      ushort4 z = {0, 0, 0, 0};
      *(ushort4*)(xn2 + (size_t)t * DIN + d) = z;
      *(ushort4*)(xn2 + (size_t)t * DIN + d + 4) = z;
    }
  }
}

// RoPE tables in double precision (match numpy)
__global__ __launch_bounds__(256) void k_rope_table(float* __restrict__ sin_t,
                                                    float* __restrict__ cos_t) {
  int idx = blockIdx.x * 256 + threadIdx.x;   // 1024*64
  int l = idx >> 6, j = idx & 63;
  double freq = pow(10000.0, (double)j / 64.0);
  float arg = (float)l * (float)freq;
  double a = (double)arg;
  sin_t[idx] = (float)sin(a);
  cos_t[idx] = (float)cos(a);
}

// ======== shared staging macros (identical in both cores; R11-verified) ========

#define GROW_A(s) (wr * 128 + (s) * 32 + wc * 8)
#define GROW_B(s) (wid * 32 + (s) * 8)

#define STG_PAIR(s, At2, Bt2, dA, dB)                                              \
  do {                                                                             \
    __builtin_amdgcn_global_load_lds(                                              \
        (AS1 unsigned int*)((At2) + (size_t)(GROW_A(s) + srow) * lda + scol),      \
        (AS3 unsigned int*)((dA) + GROW_A(s) * 64), 16, 0, 0);                     \
    __builtin_amdgcn_global_load_lds(                                              \
        (AS1 unsigned int*)((Bt2) + (size_t)(GROW_B(s) + srow) * ldb + scol),      \
        (AS3 unsigned int*)((dB) + GROW_B(s) * 64), 16, 0, 0);                     \
  } while (0)

#define BAR_FENCE()                                                                \
  do { __builtin_amdgcn_s_barrier(); asm volatile("" ::: "memory"); } while (0)

// ======== core A: 16x16x32 MFMA double-buffer (R13-verified; 0 conflicts) — uv ========

#define RD_A16(dst, cbuf, q)                                                       \
  do {                                                                             \
    _Pragma("unroll") for (int r_ = 0; r_ < 2; ++r_)                               \
    _Pragma("unroll") for (int h_ = 0; h_ < 2; ++h_)                               \
      dst[r_][h_] = *(const bf16x8*)((cbuf) + (wr * 128 + (q) * 32 + r_ * 16 + fr) * 64 + \
                                     (((h_ * 4 + kg) ^ fr7) * 8));                 \
  } while (0)

#define RD_B16(cbuf)                                                               \
  do {                                                                             \
    _Pragma("unroll") for (int n_ = 0; n_ < 4; ++n_)                               \
    _Pragma("unroll") for (int h_ = 0; h_ < 2; ++h_)                               \
      breg[n_][h_] = *(const bf16x8*)((cbuf) + (wc * 64 + n_ * 16 + fr) * 64 +     \
                                      (((h_ * 4 + kg) ^ fr7) * 8));                \
  } while (0)

#define MFMA16T(s, areg)                                                           \
  do {                                                                             \
    __builtin_amdgcn_s_setprio(1);                                                 \
    _Pragma("unroll") for (int r_ = 0; r_ < 2; ++r_)                               \
    _Pragma("unroll") for (int n_ = 0; n_ < 4; ++n_)                               \
    _Pragma("unroll") for (int h_ = 0; h_ < 2; ++h_)                               \
      acc[(s) * 2 + r_][n_] = __builtin_amdgcn_mfma_f32_16x16x32_bf16(             \
          areg[r_][h_], breg[n_][h_], acc[(s) * 2 + r_][n_], 0, 0, 0);             \
    __builtin_amdgcn_s_setprio(0);                                                 \
  } while (0)

#define TILE_STEP16(CA, CB, OA, OB, T)                                             \
  do {                                                                             \
    const bool st_ = ((T) + 2) < nt;                                               \
    const bool more_ = ((T) + 1) < nt;                                             \
    const u16* At2_ = A + (size_t)((T) + 2) * 64;                                  \
    const u16* Bt2_ = B + (size_t)((T) + 2) * 64;                                  \
    MFMA16T(0, ac);                                                                \
    RD_A16(an, CA, 1);                                                             \
    BAR_FENCE();                                                                   \
    if (st_) STG_PAIR(0, At2_, Bt2_, CA, CB);                                      \
    MFMA16T(1, an);                                                                \
    RD_A16(ac, CA, 2);                                                             \
    BAR_FENCE();                                                                   \
    if (st_) STG_PAIR(1, At2_, Bt2_, CA, CB);                                      \
    MFMA16T(2, ac);                                                                \
    RD_A16(an, CA, 3);                                                             \
    BAR_FENCE();                                                                   \
    if (st_) STG_PAIR(2, At2_, Bt2_, CA, CB);                                      \
    MFMA16T(3, an);                                                                \
    if (st_) asm volatile("s_waitcnt vmcnt(6)" ::: "memory");                      \
    else     asm volatile("s_waitcnt vmcnt(0)" ::: "memory");                      \
    BAR_FENCE();                                                                   \
    if (st_) STG_PAIR(3, At2_, Bt2_, CA, CB);                                      \
    if (more_) { RD_B16(OB); RD_A16(ac, OA, 0); }                                  \
  } while (0)

__device__ __forceinline__ void gemm256p16(const u16* __restrict__ A, int lda,
                                           const u16* __restrict__ B, int ldb,
                                           int K, u16* smem, f32x4 (&acc)[8][4]) {
  const int tid = threadIdx.x;
  const int lane = tid & 63, wid = tid >> 6;
  const int wr = wid >> 2, wc = wid & 3;
  const int fr = lane & 15, kg = lane >> 4, fr7 = fr & 7;
  const int srow = lane >> 3;
  const int scol = ((lane & 7) ^ srow) * 8;
  u16* const A0 = smem;
  u16* const B0 = smem + 16384;
  u16* const A1 = smem + 32768;
  u16* const B1 = smem + 49152;
  const int nt = K >> 6;

#pragma unroll
  for (int s = 0; s < 4; ++s) STG_PAIR(s, A, B, A0, B0);
#pragma unroll
  for (int s = 0; s < 4; ++s) STG_PAIR(s, A + 64, B + 64, A1, B1);
  asm volatile("s_waitcnt vmcnt(8)" ::: "memory");
  BAR_FENCE();

  bf16x8 breg[4][2], ac[2][2], an[2][2];
  RD_B16(B0);
  RD_A16(ac, A0, 0);

  for (int tt = 0; tt < nt; tt += 2) {
    TILE_STEP16(A0, B0, A1, B1, tt);
    TILE_STEP16(A1, B1, A0, B0, tt + 1);
  }
}

// ======== core B: 32x32x16 MFMA double-buffer (R14/R15-verified) — qk/pv/out ========

#define RD_A32(dst, cbuf, q)                                                       \
  do {                                                                             \
    _Pragma("unroll") for (int kk_ = 0; kk_ < 4; ++kk_)                            \
      dst[kk_] = *(const bf16x8*)((cbuf) + (wr * 128 + (q) * 32 + l31) * 64 +      \
                                  (((kk_ * 2 + hi) ^ l7) * 8));                    \
  } while (0)

#define RD_B32(cbuf)                                                               \
  do {                                                                             \
    _Pragma("unroll") for (int np_ = 0; np_ < 2; ++np_)                            \
    _Pragma("unroll") for (int kk_ = 0; kk_ < 4; ++kk_)                            \
      breg[np_][kk_] = *(const bf16x8*)((cbuf) + (wc * 64 + np_ * 32 + l31) * 64 + \
                                        (((kk_ * 2 + hi) ^ l7) * 8));              \
  } while (0)

#define MFMA8(s, areg)                                                             \
  do {                                                                             \
    __builtin_amdgcn_s_setprio(1);                                                 \
    _Pragma("unroll") for (int kk_ = 0; kk_ < 4; ++kk_)                            \
    _Pragma("unroll") for (int np_ = 0; np_ < 2; ++np_)                            \
      acc[s][np_] = __builtin_amdgcn_mfma_f32_32x32x16_bf16(                       \
          areg[kk_], breg[np_][kk_], acc[s][np_], 0, 0, 0);                        \
    __builtin_amdgcn_s_setprio(0);                                                 \
  } while (0)

#define TILE_STEP32(CA, CB, OA, OB, T)                                             \
  do {                                                                             \
    const bool st_ = ((T) + 2) < nt;                                               \
    const bool more_ = ((T) + 1) < nt;                                             \
    const u16* At2_ = A + (size_t)((T) + 2) * 64;                                  \
    const u16* Bt2_ = B + (size_t)((T) + 2) * 64;                                  \
    MFMA8(0, ac);                                                                  \
    RD_A32(an, CA, 1);                                                             \
    BAR_FENCE();                                                                   \
    if (st_) STG_PAIR(0, At2_, Bt2_, CA, CB);                                      \
    MFMA8(1, an);                                                                  \
    RD_A32(ac, CA, 2);                                                             \
    BAR_FENCE();                                                                   \
    if (st_) STG_PAIR(1, At2_, Bt2_, CA, CB);                                      \
    MFMA8(2, ac);                                                                  \
    RD_A32(an, CA, 3);                                                             \
    BAR_FENCE();                                                                   \
    if (st_) STG_PAIR(2, At2_, Bt2_, CA, CB);                                      \
    MFMA8(3, an);                                                                  \
    if (st_) asm volatile("s_waitcnt vmcnt(6)" ::: "memory");                      \
    else     asm volatile("s_waitcnt vmcnt(0)" ::: "memory");                      \
    BAR_FENCE();                                                                   \
    if (st_) STG_PAIR(3, At2_, Bt2_, CA, CB);                                      \
    if (more_) { RD_B32(OB); RD_A32(ac, OA, 0); }                                  \
  } while (0)

__device__ __forceinline__ void gemm256p32(const u16* __restrict__ A, int lda,
                                           const u16* __restrict__ B, int ldb,
                                           int K, u16* smem, f32x16 (&acc)[4][2]) {
  const int tid = threadIdx.x;
  const int lane = tid & 63, wid = tid >> 6;
  const int wr = wid >> 2, wc = wid & 3;
  const int l31 = lane & 31, hi = lane >> 5, l7 = lane & 7;
  const int srow = lane >> 3;
  const int scol = ((lane & 7) ^ srow) * 8;
  u16* const A0 = smem;
  u16* const B0 = smem + 16384;
  u16* const A1 = smem + 32768;
  u16* const B1 = smem + 49152;
  const int nt = K >> 6;

#pragma unroll
  for (int s = 0; s < 4; ++s) STG_PAIR(s, A, B, A0, B0);
#pragma unroll
  for (int s = 0; s < 4; ++s) STG_PAIR(s, A + 64, B + 64, A1, B1);
  asm volatile("s_waitcnt vmcnt(8)" ::: "memory");
  BAR_FENCE();

  bf16x8 breg[2][4], ac[4], an[4];
  RD_B32(B0);
  RD_A32(ac, A0, 0);

  for (int tt = 0; tt < nt; tt += 2) {
    TILE_STEP32(A0, B0, A1, B1, tt);
    TILE_STEP32(A1, B1, A0, B0, tt + 1);
  }
}

// GEMM1: uv = silu(xn2 @ uv_w^T). 16x16 core. Grid 1152 = 8 XCDs x 16 M x 9 N.
// N-tiles 0-3 -> u; 4-7 -> vt[b][e][l]; tile 8 -> fused gamma/beta+RoPE -> q,k.
__global__ __launch_bounds__(512, 2) void k_gemm_uv(const u16* __restrict__ xn2,
                                                    const u16* __restrict__ wbf,
                                                    u16* __restrict__ u, u16* __restrict__ vt,
                                                    const float* __restrict__ gamma,
                                                    const float* __restrict__ beta,
                                                    const float* __restrict__ sin_t,
                                                    const float* __restrict__ cos_t,
                                                    u16* __restrict__ qout,
                                                    u16* __restrict__ kout) {
  __shared__ __align__(16) u16 smem[65536];
  f32x4 acc[8][4] = {};
  int bid = blockIdx.x;
  int xcd = bid & 7;
  int off = bid >> 3;                 // 0..143
  int m0 = (xcd * 16 + off / 9) * 256;
  int n0 = (off % 9) * 256;
  gemm256p16(xn2 + (size_t)m0 * DIN, DIN, wbf + (size_t)n0 * DIN, DIN, DIN, smem, acc);
  int lane = threadIdx.x & 63, wid = threadIdx.x >> 6;
  int wr = wid >> 2, wc = wid & 3;
  int cb = n0 + wc * 64 + (lane & 15);
  int rb = m0 + wr * 128 + (lane >> 4) * 4;
  if (n0 < EDIM) {                       // u columns
#pragma unroll
    for (int mm = 0; mm < 8; ++mm)
#pragma unroll
      for (int n = 0; n < 4; ++n) {
        int c = cb + n * 16;
#pragma unroll
        for (int j = 0; j < 4; ++j) {
          int r = rb + mm * 16 + j;
          u[(size_t)r * EDIM + c] = f2bf(fast_silu(acc[mm][n][j]));
        }
      }
  } else if (n0 < 2 * EDIM) {            // v columns -> transposed store
    int b = m0 >> 10;
    u16* vtb = vt + (size_t)b * (EDIM * LSEQ);
#pragma unroll
    for (int mm = 0; mm < 8; ++mm) {
      int l0 = (rb + mm * 16) & (LSEQ - 1);
#pragma unroll
      for (int n = 0; n < 4; ++n) {
        int e = cb + n * 16 - EDIM;
        ushort4 o;
        o.x = f2bf(fast_silu(acc[mm][n][0]));
        o.y = f2bf(fast_silu(acc[mm][n][1]));
        o.z = f2bf(fast_silu(acc[mm][n][2]));
        o.w = f2bf(fast_silu(acc[mm][n][3]));
        *(ushort4*)(vtb + (size_t)e * LSEQ + l0) = o;
      }
    }
  } else {                               // base tile -> fused gamma/beta + RoPE -> q,k
    u16* sbase = smem;                   // [256][136] padded
    if (wc < 2) {
#pragma unroll
      for (int mm = 0; mm < 8; ++mm)
#pragma unroll
        for (int n = 0; n < 4; ++n) {
          int c = wc * 64 + (lane & 15) + n * 16;      // 0..127 local
#pragma unroll
          for (int j = 0; j < 4; ++j) {
            int r = wr * 128 + mm * 16 + (lane >> 4) * 4 + j;  // 0..255 local
            sbase[r * 136 + c] = f2bf(fast_silu(acc[mm][n][j]));
          }
        }
    }
    __syncthreads();
    int tid = threadIdx.x;
    int j = tid & 63;
    float g0 = gamma[j], g1 = gamma[64 + j], g2 = gamma[128 + j], g3 = gamma[192 + j];
    float e0 = beta[j],  e1 = beta[64 + j],  e2 = beta[128 + j],  e3 = beta[192 + j];
#pragma unroll 4
    for (int i = 0; i < 32; ++i) {
      int row = (tid >> 6) + i * 8;      // covers 0..255
      int t = m0 + row;
      int l = t & (LSEQ - 1);
      float b1 = bf2f(sbase[row * 136 + j]);
      float b2 = bf2f(sbase[row * 136 + j + 64]);
      float sn = sin_t[l * 64 + j], cs = cos_t[l * 64 + j];
      float y1 = b1 * g0 + e0, y2 = b2 * g1 + e1;
      qout[(size_t)t * SDIM + j]      = f2bf(y1 * cs - y2 * sn);
      qout[(size_t)t * SDIM + j + 64] = f2bf(y2 * cs + y1 * sn);
      y1 = b1 * g2 + e2; y2 = b2 * g3 + e3;
      kout[(size_t)t * SDIM + j]      = f2bf(y1 * cs - y2 * sn);
      kout[(size_t)t * SDIM + j + 64] = f2bf(y2 * cs + y1 * sn);
    }
  }
}

// 32x32 C/D layout: r = m0 + wr*128 + q*32 + g*8 + hi*4 + j (reg g*4+j);
//                   c = n0 + wc*64 + np*32 + l31

// GEMM2: scores = relu((q k^T + w)/sqrt(S))^2.  32x32 core, nt=2.
// Grid 256 = 8 XCDs x 2 batches x 16 tiles (16 batches per launch).
__global__ __launch_bounds__(512, 2) void k_gemm_qk(const u16* __restrict__ q_,
                                                    const u16* __restrict__ k_,
                                                    const float* __restrict__ w,
                                                    u16* __restrict__ scores) {
  __shared__ __align__(16) u16 smem[65536];
  f32x16 acc[4][2] = {};
  int bid = blockIdx.x;
  int xcd = bid & 7;
  int off = bid >> 3;                    // 0..31
  int b = xcd * 2 + (off >> 4);          // chunk-local batch
  int t = off & 15;
  int m0 = (t >> 2) * 256, n0 = (t & 3) * 256;
  gemm256p32(q_ + (size_t)(b * LSEQ + m0) * SDIM, SDIM,
             k_ + (size_t)(b * LSEQ + n0) * SDIM, SDIM,
             SDIM, smem, acc);
  int lane = threadIdx.x & 63, wid = threadIdx.x >> 6;
  int wr = wid >> 2, wc = wid & 3;
  int l31 = lane & 31, hi = lane >> 5;
  const float inv_sqrt_s = 0.08838834764831845f;
  u16* sc_b = scores + (size_t)b * LSEQ * LSEQ;
#pragma unroll
  for (int q = 0; q < 4; ++q)
#pragma unroll
    for (int np = 0; np < 2; ++np) {
      int c = n0 + wc * 64 + np * 32 + l31;
#pragma unroll
      for (int g = 0; g < 4; ++g)
#pragma unroll
        for (int j = 0; j < 4; ++j) {
          int r = m0 + wr * 128 + q * 32 + g * 8 + hi * 4 + j;
          float val = (acc[q][np][g * 4 + j] + w[c - r + (LSEQ - 1)]) * inv_sqrt_s;
          val = fmaxf(val, 0.0f);
          sc_b[(size_t)r * LSEQ + c] = f2bf(val * val);
        }
    }
}

// GEMM3: u_io <- u_io .* (scores @ v).  32x32 core.
// Grid 256 = 8 XCDs x 2 batches x 16 tiles (16 batches per launch).
__global__ __launch_bounds__(512, 2) void k_gemm_pv(const u16* __restrict__ scores,
                                                    const u16* __restrict__ vt,
                                                    u16* u_io) {
  __shared__ __align__(16) u16 smem[65536];
  f32x16 acc[4][2] = {};
  int bid = blockIdx.x;
  int xcd = bid & 7;
  int off = bid >> 3;                    // 0..31
  int b = xcd * 2 + (off >> 4);          // chunk-local batch
  int t = off & 15;
  int m0 = (t >> 2) * 256, n0 = (t & 3) * 256;
  gemm256p32(scores + (size_t)b * LSEQ * LSEQ + (size_t)m0 * LSEQ, LSEQ,
             vt + (size_t)b * LSEQ * EDIM + (size_t)n0 * LSEQ, LSEQ,
             LSEQ, smem, acc);
  int lane = threadIdx.x & 63, wid = threadIdx.x >> 6;
  int wr = wid >> 2, wc = wid & 3;
  int l31 = lane & 31, hi = lane >> 5;
#pragma unroll
  for (int q = 0; q < 4; ++q)
#pragma unroll
    for (int np = 0; np < 2; ++np) {
      int c = n0 + wc * 64 + np * 32 + l31;
#pragma unroll
      for (int g = 0; g < 4; ++g)
#pragma unroll
        for (int j = 0; j < 4; ++j) {
          int r = m0 + wr * 128 + q * 32 + g * 8 + hi * 4 + j;
          size_t idx = (size_t)(b * LSEQ + r) * EDIM + c;
          u_io[idx] = f2bf(acc[q][np][g * 4 + j] * bf2f(u_io[idx]));
        }
    }
}

// GEMM4: out = x*res_scale + (attn @ o_w^T)*layer_scale.  32x32 core.
// Grid 256 = 8 XCDs x 16 M-tiles x 2 N-tiles.
__global__ __launch_bounds__(512, 2) void k_gemm_out(const u16* __restrict__ attn,
                                                     const u16* __restrict__ owbf,
                                                     const float* __restrict__ x,
                                                     const float* __restrict__ res_scale,
                                                     const float* __restrict__ layer_scale,
                                                     float* __restrict__ out) {
  __shared__ __align__(16) u16 smem[65536];
  f32x16 acc[4][2] = {};
  int bid = blockIdx.x;
  int xcd = bid & 7;
  int off = bid >> 3;                 // 0..31
  int m0 = (xcd * 16 + (off >> 1)) * 256;
  int n0 = (off & 1) * 256;
  gemm256p32(attn + (size_t)m0 * EDIM, EDIM, owbf + (size_t)n0 * EDIM, EDIM,
             EDIM, smem, acc);
  int lane = threadIdx.x & 63, wid = threadIdx.x >> 6;
  int wr = wid >> 2, wc = wid & 3;
  int l31 = lane & 31, hi = lane >> 5;
#pragma unroll
  for (int q = 0; q < 4; ++q)
#pragma unroll
    for (int np = 0; np < 2; ++np) {
      int c = n0 + wc * 64 + np * 32 + l31;
#pragma unroll
      for (int g = 0; g < 4; ++g)
#pragma unroll
        for (int j = 0; j < 4; ++j) {
          int r = m0 + wr * 128 + q * 32 + g * 8 + hi * 4 + j;
          out[(size_t)r * DIN + c] =
              x[(size_t)r * DIN + c] * res_scale[c] + acc[q][np][g * 4 + j] * layer_scale[c];
        }
    }
}

// ---------------- launch ----------------

extern "C" void kernel_launch(void* const* d_in, const int* in_sizes, int n_in,
                              void* d_out, int out_size, void* d_ws, size_t ws_size,
                              hipStream_t stream) {
  const float* x          = (const float*)d_in[0];
  const float* uv_w       = (const float*)d_in[1];
  const float* o_w        = (const float*)d_in[2];
  const float* gamma      = (const float*)d_in[3];
  const float* beta       = (const float*)d_in[4];
  const float* w          = (const float*)d_in[5];
  const float* g          = (const float*)d_in[6];
  const float* res_scale  = (const float*)d_in[7];
  const float* layer_scale= (const float*)d_in[8];
  float* out = (float*)d_out;

  char* ws = (char*)d_ws;
  // workspace layout (bytes), peak ~180 MB (< proven-good 197).
  u16* xn2    = (u16*)(ws + 0);            // 32 MB, dead after gemm_uv
  u16* scores = (u16*)(ws + 0);            // 32 MB (aliases dead xn2)
  u16* q      = (u16*)(ws + 33554432);     // 8 MB
  u16* k      = (u16*)(ws + 41943040);     // 8 MB
  u16* u_io   = (u16*)(ws + 50331648);     // 64 MB: u, gated in place -> attn
  u16* vt     = (u16*)(ws + 117440512);    // 64 MB: v^T per batch
  u16* uvw_bf = (u16*)(ws + 184549376);    // 2.125 MB (+slack for tile-8 pad reads)
  u16* ow_bf  = (u16*)(ws + 187170816);    // 1 MB
  float* sin_t = (float*)(ws + 188219392); // 256 KB
  float* cos_t = (float*)(ws + 188481536); // 256 KB

  // prep (one conversion launch, one rope launch, one wave-per-token normshift)
  k_wconv<<<dim3((NUV * DIN / 4 + DIN * EDIM / 4 + 255) / 256), 256, 0, stream>>>(
      uv_w, uvw_bf, NUV * DIN / 4, o_w, ow_bf, DIN * EDIM / 4);
  k_rope_table<<<dim3(LSEQ * 64 / 256), 256, 0, stream>>>(sin_t, cos_t);
  k_normshift<<<dim3(NTOK / 4), 256, 0, stream>>>(x, g, xn2);

  // uv projection + silu + fused qk build (16x16 core)
  k_gemm_uv<<<dim3(1152), 512, 0, stream>>>(xn2, uvw_bf, u_io, vt,
                                            gamma, beta, sin_t, cos_t, q, k);

  // scores + pv, chunked by 16 batches (32x32 core)
  for (int ch = 0; ch < NB / CHUNK; ++ch) {
    size_t tok0 = (size_t)ch * CHUNK * LSEQ;
    k_gemm_qk<<<dim3(256), 512, 0, stream>>>(q + tok0 * SDIM, k + tok0 * SDIM, w, scores);
    k_gemm_pv<<<dim3(256), 512, 0, stream>>>(scores, vt + tok0 * EDIM, u_io + tok0 * EDIM);
  }

  // final projection + residual (32x32 core)
  k_gemm_out<<<dim3(256), 512, 0, stream>>>(u_io, ow_bf, x, res_scale, layer_scale, out);
}